// Round 4
// baseline (36488.849 us; speedup 1.0000x reference)
//
#include <hip/hip_runtime.h>
#include <math.h>

#define B_ 32
#define T_ 512
#define D_ 512
#define H_ 512
#define G_ 2048        // 4*H
#define M_ (B_ * T_)   // 16384

typedef _Float16 half2v __attribute__((ext_vector_type(2)));

static __device__ __forceinline__ unsigned short f2h(float f) {
  return __builtin_bit_cast(unsigned short, (_Float16)f);
}
static __device__ __forceinline__ float h2f(unsigned short u) {
  return (float)__builtin_bit_cast(_Float16, u);
}
static __device__ __forceinline__ unsigned int packh2(float a, float b) {
  return (unsigned int)f2h(a) | ((unsigned int)f2h(b) << 16);
}

// -----------------------------------------------------------------------------
// Pack Wh fp32 [512][2048] -> wpack f16 pairs [dir][part][kp=256][c=512]
//   col(part,c) = (c>>7)*512 + part*128 + (c&127)   (c = gate*128 + u)
//   uint = ( f16(Wh[2kp][col]), f16(Wh[2kp+1][col]) )
// -----------------------------------------------------------------------------
__global__ __launch_bounds__(512) void pack_wh(
    const float* __restrict__ Wh_f, const float* __restrict__ Wh_b,
    unsigned int* __restrict__ wpack)
{
  int gid = blockIdx.x * 512 + threadIdx.x;   // 0 .. 2*4*256*512-1
  int c    = gid & 511;
  int kp   = (gid >> 9) & 255;
  int part = (gid >> 17) & 3;
  int dir  = gid >> 19;
  const float* Wh = dir ? Wh_b : Wh_f;
  int col = ((c >> 7) << 9) + part * 128 + (c & 127);
  const float* src = Wh + (size_t)(2 * kp) * G_ + col;
  wpack[gid] = packh2(src[0], src[G_]);
}

// zero hbuf (32768 uints) + flags (8192 ints) = 40960 words
__global__ __launch_bounds__(512) void zero_ws(unsigned int* p) {
  p[blockIdx.x * 512 + threadIdx.x] = 0u;
}

// -----------------------------------------------------------------------------
// GEMM: xs[dir][m][pc] (f16, packed-col layout) = A_dir[m][:] @ Wi_dir + bias
//   pc = part*512 + gate*128 + u  where original col = gate*512 + part*128 + u
// -----------------------------------------------------------------------------
__global__ __launch_bounds__(256) void xs_gemm(
    const float* __restrict__ x, const int* __restrict__ lengths,
    const float* __restrict__ Wi_f, const float* __restrict__ bf,
    const float* __restrict__ Wi_b, const float* __restrict__ bb,
    unsigned int* __restrict__ xs)   // f16 pairs, 1024 uints per row
{
  const int dir = blockIdx.z;
  const float* Wi   = dir ? Wi_b : Wi_f;
  const float* bias = dir ? bb : bf;
  unsigned int* outp = xs + (size_t)dir * ((size_t)M_ * 1024);
  const int m0 = blockIdx.x * 64;
  const int n0 = blockIdx.y * 64;

  __shared__ __attribute__((aligned(16))) float As[32][68];
  __shared__ __attribute__((aligned(16))) float Bs[32][68];

  const int tid = threadIdx.x;
  const int tx = tid & 15, ty = tid >> 4;
  const int arow = tid >> 3;
  const int acol = (tid & 7) << 2;
  const int brow = tid >> 4;
  const int bcol = (tid & 15) << 2;

  size_t abase[2];
#pragma unroll
  for (int r = 0; r < 2; ++r) {
    int m = m0 + arow + r * 32;
    int bidx = m >> 9, t = m & 511;
    int s = t;
    if (dir) { int l = lengths[bidx]; s = l - 1 - t; if (s < 0) s += T_; }
    abase[r] = ((size_t)bidx * T_ + s) * D_;
  }

  float acc[4][4] = {{0.f}};

  for (int k0 = 0; k0 < D_; k0 += 32) {
#pragma unroll
    for (int r = 0; r < 2; ++r) {
      float4 av = *(const float4*)(x + abase[r] + (k0 + acol));
      int row = arow + r * 32;
      As[acol + 0][row] = av.x;
      As[acol + 1][row] = av.y;
      As[acol + 2][row] = av.z;
      As[acol + 3][row] = av.w;
    }
#pragma unroll
    for (int r = 0; r < 2; ++r) {
      int kk = brow + r * 16;
      float4 bv = *(const float4*)(Wi + (size_t)(k0 + kk) * G_ + n0 + bcol);
      *(float4*)&Bs[kk][bcol] = bv;
    }
    __syncthreads();
#pragma unroll
    for (int kk = 0; kk < 32; ++kk) {
      float4 a4 = *(const float4*)&As[kk][ty << 2];
      float4 b4 = *(const float4*)&Bs[kk][tx << 2];
      float a_[4] = {a4.x, a4.y, a4.z, a4.w};
      float b_[4] = {b4.x, b4.y, b4.z, b4.w};
#pragma unroll
      for (int i = 0; i < 4; ++i)
#pragma unroll
        for (int j = 0; j < 4; ++j)
          acc[i][j] = fmaf(a_[i], b_[j], acc[i][j]);
    }
    __syncthreads();
  }

  // epilogue: remap 64-col tile (one gate, one part, u0=0|64) to packed layout
  const int gate = n0 >> 9;
  const int part = (n0 & 511) >> 7;
  const int u0   = n0 & 127;
  const int pcb  = part * 512 + gate * 128 + u0;     // even
  float4 bias4 = *(const float4*)(bias + n0 + (tx << 2));
  float bb4[4] = {bias4.x, bias4.y, bias4.z, bias4.w};
#pragma unroll
  for (int i = 0; i < 4; ++i) {
    int m = m0 + (ty << 2) + i;
    uint2 o;
    o.x = packh2(acc[i][0] + bb4[0], acc[i][1] + bb4[1]);
    o.y = packh2(acc[i][2] + bb4[2], acc[i][3] + bb4[3]);
    *(uint2*)(outp + (size_t)m * 1024 + (pcb >> 1) + tx * 2) = o;
  }
}

// -----------------------------------------------------------------------------
// Recurrence v4: 256 WGs = 4 per (b,dir), one 128-unit slice each.
// bid mapping (XCD RR heuristic): xcd=bid&7 -> dir=xcd>>2, b_lo=xcd&3;
// sg_=bid>>3 -> part=sg_&3, b=(sg_>>2)*4+b_lo. 32 WGs/XCD, one dir per
// XCD half -> 2 MB f16 weights L2-resident per XCD.
// Per step: stage 256 h-pairs (1KB) -> 4 kp-subgroups x 128 cols matvec from
// L2 weights -> LDS partial reduce -> gates (128 thr) -> write 64 h-pairs ->
// 4-flag release/acquire barrier (double-buffered hbuf).
// -----------------------------------------------------------------------------
__global__ __launch_bounds__(512) void lstm_rec4(
    const unsigned int* __restrict__ xs,      // f16 pairs
    const unsigned int* __restrict__ wpack,   // f16 pairs
    unsigned int* __restrict__ hbuf,          // [2][64grp][256] f16 pairs
    int* __restrict__ flags,                  // [64grp][4][32pad]
    const int* __restrict__ lengths,
    float* __restrict__ out)
{
  const int bid  = blockIdx.x;
  const int xcd  = bid & 7;
  const int dir  = xcd >> 2;
  const int b_lo = xcd & 3;
  const int sg_  = bid >> 3;
  const int part = sg_ & 3;
  const int b    = ((sg_ >> 2) << 2) + b_lo;
  const int grp  = (dir << 5) + b;

  __shared__ unsigned int hpair[256];
  __shared__ float y_lds[2048];
  __shared__ float h_loc[128];

  const int tid = threadIdx.x;
  const int ksg = tid >> 7;            // kp quarter 0..3
  const int c4  = (tid & 127) << 2;    // col base within part's 512
  const int kp0 = ksg << 6;

  const unsigned int* wp = wpack + ((size_t)((dir << 2) + part) << 17) + c4;
  const unsigned short* xrow0 = (const unsigned short*)xs
      + ((size_t)(dir * M_ + b * T_) << 11) + part * 512;
  int* gflags = flags + (grp << 7);
  int* myflag = gflags + (part << 5);

  const int l = lengths[b];
  float c = 0.f;

  for (int t = 0; t < T_; ++t) {
    // stage h (f16 pairs) for this step
    if (tid < 256) {
      const unsigned int* hb_r = hbuf + (((size_t)(t & 1) << 6) + grp) * 256;
      hpair[tid] = (t == 0) ? 0u : hb_r[tid];
    }
    __syncthreads();

    // matvec: this subgroup's 64 k-pairs x this thread's 4 columns
    float4 acc = make_float4(0.f, 0.f, 0.f, 0.f);
#pragma unroll 8
    for (int i = 0; i < 64; ++i) {
      uint4 w = *(const uint4*)(wp + ((kp0 + i) << 9));
      half2v hh = __builtin_bit_cast(half2v, hpair[kp0 + i]);
      float h0 = (float)hh.x, h1 = (float)hh.y;
      half2v wx = __builtin_bit_cast(half2v, w.x);
      half2v wy = __builtin_bit_cast(half2v, w.y);
      half2v wz = __builtin_bit_cast(half2v, w.z);
      half2v ww = __builtin_bit_cast(half2v, w.w);
      acc.x = fmaf(h0, (float)wx.x, acc.x); acc.x = fmaf(h1, (float)wx.y, acc.x);
      acc.y = fmaf(h0, (float)wy.x, acc.y); acc.y = fmaf(h1, (float)wy.y, acc.y);
      acc.z = fmaf(h0, (float)wz.x, acc.z); acc.z = fmaf(h1, (float)wz.y, acc.z);
      acc.w = fmaf(h0, (float)ww.x, acc.w); acc.w = fmaf(h1, (float)ww.y, acc.w);
    }
    *(float4*)&y_lds[(ksg << 9) + c4] = acc;
    __syncthreads();

    // gates: thread u (<128) owns hidden unit part*128+u
    if (tid < 128) {
      const unsigned short* xr = xrow0 + ((size_t)t << 11) + tid;
      float ys[4];
#pragma unroll
      for (int gg = 0; gg < 4; ++gg) {
        int cc = (gg << 7) + tid;
        ys[gg] = y_lds[cc] + y_lds[512 + cc] + y_lds[1024 + cc] + y_lds[1536 + cc]
               + h2f(xr[gg << 7]);
      }
      float iv = 1.f / (1.f + expf(-ys[0]));
      float fv = 1.f / (1.f + expf(-ys[1]));
      float gv = tanhf(ys[2]);
      float ov = 1.f / (1.f + expf(-ys[3]));
      c = fv * c + iv * gv;
      float hv = ov * tanhf(c);
      h_loc[tid] = hv;
      int tout = t;
      if (dir) { tout = l - 1 - t; if (tout < 0) tout += T_; }
      out[((size_t)(b * T_ + tout) << 10) + (dir << 9) + (part << 7) + tid] = hv;
    }
    __syncthreads();

    // exchange h + 4-WG barrier (skip after last step)
    if (t < T_ - 1) {
      if (tid < 64) {
        unsigned int* hb_w = hbuf + (((size_t)((t + 1) & 1) << 6) + grp) * 256;
        hb_w[(part << 6) + tid] = packh2(h_loc[2 * tid], h_loc[2 * tid + 1]);
      }
      __threadfence();
      __syncthreads();
      if (tid == 0)
        __hip_atomic_store(myflag, t + 1, __ATOMIC_RELEASE, __HIP_MEMORY_SCOPE_AGENT);
      if (tid < 4) {
        while (__hip_atomic_load(gflags + (tid << 5), __ATOMIC_ACQUIRE,
                                 __HIP_MEMORY_SCOPE_AGENT) < t + 1)
          __builtin_amdgcn_s_sleep(1);
      }
      __syncthreads();
      __threadfence();
    }
  }
}

extern "C" void kernel_launch(void* const* d_in, const int* in_sizes, int n_in,
                              void* d_out, int out_size, void* d_ws, size_t ws_size,
                              hipStream_t stream) {
  const float* x       = (const float*)d_in[0];
  const int*   lengths = (const int*)d_in[1];
  const float* Wi_f    = (const float*)d_in[2];
  const float* Wh_f    = (const float*)d_in[3];
  const float* b_f     = (const float*)d_in[4];
  const float* Wi_b    = (const float*)d_in[5];
  const float* Wh_b    = (const float*)d_in[6];
  const float* b_b     = (const float*)d_in[7];
  float* out = (float*)d_out;

  unsigned int* xs    = (unsigned int*)d_ws;            // 128 MiB (f16 pairs)
  unsigned int* wpack = xs + (size_t)2 * M_ * 1024;     // 4 MiB
  unsigned int* hbuf  = wpack + (size_t)2 * 4 * 256 * 512;  // 128 KiB
  int*          flags = (int*)(hbuf + 2 * 64 * 256);    // 32 KiB

  pack_wh<<<dim3(2048), 512, 0, stream>>>(Wh_f, Wh_b, wpack);
  zero_ws<<<dim3(80), 512, 0, stream>>>(hbuf);   // hbuf (32768) + flags (8192)

  dim3 g1(M_ / 64, G_ / 64, 2);
  xs_gemm<<<g1, 256, 0, stream>>>(x, lengths, Wi_f, b_f, Wi_b, b_b, xs);

  lstm_rec4<<<dim3(256), 512, 0, stream>>>(xs, wpack, hbuf, flags, lengths, out);
}

// Round 5
// 4406.335 us; speedup vs baseline: 8.2810x; 8.2810x over previous
//
#include <hip/hip_runtime.h>
#include <math.h>

#define B_ 32
#define T_ 512
#define D_ 512
#define H_ 512
#define G_ 2048        // 4*H
#define M_ (B_ * T_)   // 16384

typedef _Float16 half2v __attribute__((ext_vector_type(2)));

static __device__ __forceinline__ unsigned short f2h(float f) {
  return __builtin_bit_cast(unsigned short, (_Float16)f);
}
static __device__ __forceinline__ float h2f(unsigned short u) {
  return (float)__builtin_bit_cast(_Float16, u);
}
static __device__ __forceinline__ unsigned int packh2(float a, float b) {
  return (unsigned int)f2h(a) | ((unsigned int)f2h(b) << 16);
}

// -----------------------------------------------------------------------------
// Pack Wh fp32 [512][2048] -> wpack f16 pairs [dir][part][kp=256][c=512]
// -----------------------------------------------------------------------------
__global__ __launch_bounds__(512) void pack_wh(
    const float* __restrict__ Wh_f, const float* __restrict__ Wh_b,
    unsigned int* __restrict__ wpack)
{
  int gid = blockIdx.x * 512 + threadIdx.x;   // 0 .. 2*4*256*512-1
  int c    = gid & 511;
  int kp   = (gid >> 9) & 255;
  int part = (gid >> 17) & 3;
  int dir  = gid >> 19;
  const float* Wh = dir ? Wh_b : Wh_f;
  int col = ((c >> 7) << 9) + part * 128 + (c & 127);
  const float* src = Wh + (size_t)(2 * kp) * G_ + col;
  wpack[gid] = packh2(src[0], src[G_]);
}

// zero hbuf (32768 uints) + flags (8192 ints) = 40960 words
__global__ __launch_bounds__(512) void zero_ws(unsigned int* p) {
  p[blockIdx.x * 512 + threadIdx.x] = 0u;
}

// -----------------------------------------------------------------------------
// GEMM: xs[dir][m][pc] (f16, packed-col layout) = A_dir[m][:] @ Wi_dir + bias
// -----------------------------------------------------------------------------
__global__ __launch_bounds__(256) void xs_gemm(
    const float* __restrict__ x, const int* __restrict__ lengths,
    const float* __restrict__ Wi_f, const float* __restrict__ bf,
    const float* __restrict__ Wi_b, const float* __restrict__ bb,
    unsigned int* __restrict__ xs)   // f16 pairs, 1024 uints per row
{
  const int dir = blockIdx.z;
  const float* Wi   = dir ? Wi_b : Wi_f;
  const float* bias = dir ? bb : bf;
  unsigned int* outp = xs + (size_t)dir * ((size_t)M_ * 1024);
  const int m0 = blockIdx.x * 64;
  const int n0 = blockIdx.y * 64;

  __shared__ __attribute__((aligned(16))) float As[32][68];
  __shared__ __attribute__((aligned(16))) float Bs[32][68];

  const int tid = threadIdx.x;
  const int tx = tid & 15, ty = tid >> 4;
  const int arow = tid >> 3;
  const int acol = (tid & 7) << 2;
  const int brow = tid >> 4;
  const int bcol = (tid & 15) << 2;

  size_t abase[2];
#pragma unroll
  for (int r = 0; r < 2; ++r) {
    int m = m0 + arow + r * 32;
    int bidx = m >> 9, t = m & 511;
    int s = t;
    if (dir) { int l = lengths[bidx]; s = l - 1 - t; if (s < 0) s += T_; }
    abase[r] = ((size_t)bidx * T_ + s) * D_;
  }

  float acc[4][4] = {{0.f}};

  for (int k0 = 0; k0 < D_; k0 += 32) {
#pragma unroll
    for (int r = 0; r < 2; ++r) {
      float4 av = *(const float4*)(x + abase[r] + (k0 + acol));
      int row = arow + r * 32;
      As[acol + 0][row] = av.x;
      As[acol + 1][row] = av.y;
      As[acol + 2][row] = av.z;
      As[acol + 3][row] = av.w;
    }
#pragma unroll
    for (int r = 0; r < 2; ++r) {
      int kk = brow + r * 16;
      float4 bv = *(const float4*)(Wi + (size_t)(k0 + kk) * G_ + n0 + bcol);
      *(float4*)&Bs[kk][bcol] = bv;
    }
    __syncthreads();
#pragma unroll
    for (int kk = 0; kk < 32; ++kk) {
      float4 a4 = *(const float4*)&As[kk][ty << 2];
      float4 b4 = *(const float4*)&Bs[kk][tx << 2];
      float a_[4] = {a4.x, a4.y, a4.z, a4.w};
      float b_[4] = {b4.x, b4.y, b4.z, b4.w};
#pragma unroll
      for (int i = 0; i < 4; ++i)
#pragma unroll
        for (int j = 0; j < 4; ++j)
          acc[i][j] = fmaf(a_[i], b_[j], acc[i][j]);
    }
    __syncthreads();
  }

  const int gate = n0 >> 9;
  const int part = (n0 & 511) >> 7;
  const int u0   = n0 & 127;
  const int pcb  = part * 512 + gate * 128 + u0;
  float4 bias4 = *(const float4*)(bias + n0 + (tx << 2));
  float bb4[4] = {bias4.x, bias4.y, bias4.z, bias4.w};
#pragma unroll
  for (int i = 0; i < 4; ++i) {
    int m = m0 + (ty << 2) + i;
    uint2 o;
    o.x = packh2(acc[i][0] + bb4[0], acc[i][1] + bb4[1]);
    o.y = packh2(acc[i][2] + bb4[2], acc[i][3] + bb4[3]);
    *(uint2*)(outp + (size_t)m * 1024 + (pcb >> 1) + tx * 2) = o;
  }
}

// -----------------------------------------------------------------------------
// Recurrence v5: round-4 structure (4 WGs per (b,dir), 256 WGs, L2-resident
// weight slices) but cross-WG sync via RELAXED agent-scope atomics (per-access
// L3 ops) + explicit s_waitcnt vmcnt(0) ordering. NO acquire/release fences ->
// no L2 invalidate -> weights stay L2-resident.
// -----------------------------------------------------------------------------
__global__ __launch_bounds__(512) void lstm_rec5(
    const unsigned int* __restrict__ xs,      // f16 pairs
    const unsigned int* __restrict__ wpack,   // f16 pairs
    unsigned int* __restrict__ hbuf,          // [2][64grp][256] f16 pairs
    int* __restrict__ flags,                  // [64grp][4][32pad]
    const int* __restrict__ lengths,
    float* __restrict__ out)
{
  const int bid  = blockIdx.x;
  const int xcd  = bid & 7;
  const int dir  = xcd >> 2;
  const int b_lo = xcd & 3;
  const int sg_  = bid >> 3;
  const int part = sg_ & 3;
  const int b    = ((sg_ >> 2) << 2) + b_lo;
  const int grp  = (dir << 5) + b;

  __shared__ unsigned int hpair[256];
  __shared__ float y_lds[2048];
  __shared__ float h_loc[128];

  const int tid = threadIdx.x;
  const int ksg = tid >> 7;            // kp quarter 0..3
  const int c4  = (tid & 127) << 2;    // col base within part's 512
  const int kp0 = ksg << 6;

  const unsigned int* wp = wpack + ((size_t)((dir << 2) + part) << 17) + c4;
  const unsigned short* xrow0 = (const unsigned short*)xs
      + ((size_t)(dir * M_ + b * T_) << 11) + part * 512;
  int* gflags = flags + (grp << 7);
  int* myflag = gflags + (part << 5);

  const int l = lengths[b];
  float c = 0.f;

  for (int t = 0; t < T_; ++t) {
    // stage h (f16 pairs) for this step — relaxed agent loads (L3, no inv)
    if (tid < 256) {
      unsigned int v = 0u;
      if (t != 0) {
        unsigned int* hb_r = hbuf + (((size_t)(t & 1) << 6) + grp) * 256;
        v = __hip_atomic_load(&hb_r[tid], __ATOMIC_RELAXED,
                              __HIP_MEMORY_SCOPE_AGENT);
      }
      hpair[tid] = v;
    }
    __syncthreads();

    // matvec: this subgroup's 64 k-pairs x this thread's 4 columns
    float4 acc = make_float4(0.f, 0.f, 0.f, 0.f);
#pragma unroll 8
    for (int i = 0; i < 64; ++i) {
      uint4 w = *(const uint4*)(wp + ((kp0 + i) << 9));
      half2v hh = __builtin_bit_cast(half2v, hpair[kp0 + i]);
      float h0 = (float)hh.x, h1 = (float)hh.y;
      half2v wx = __builtin_bit_cast(half2v, w.x);
      half2v wy = __builtin_bit_cast(half2v, w.y);
      half2v wz = __builtin_bit_cast(half2v, w.z);
      half2v ww = __builtin_bit_cast(half2v, w.w);
      acc.x = fmaf(h0, (float)wx.x, acc.x); acc.x = fmaf(h1, (float)wx.y, acc.x);
      acc.y = fmaf(h0, (float)wy.x, acc.y); acc.y = fmaf(h1, (float)wy.y, acc.y);
      acc.z = fmaf(h0, (float)wz.x, acc.z); acc.z = fmaf(h1, (float)wz.y, acc.z);
      acc.w = fmaf(h0, (float)ww.x, acc.w); acc.w = fmaf(h1, (float)ww.y, acc.w);
    }
    *(float4*)&y_lds[(ksg << 9) + c4] = acc;
    __syncthreads();

    // gates: thread u (<128) owns hidden unit part*128+u
    if (tid < 128) {
      const unsigned short* xr = xrow0 + ((size_t)t << 11) + tid;
      float ys[4];
#pragma unroll
      for (int gg = 0; gg < 4; ++gg) {
        int cc = (gg << 7) + tid;
        ys[gg] = y_lds[cc] + y_lds[512 + cc] + y_lds[1024 + cc] + y_lds[1536 + cc]
               + h2f(xr[gg << 7]);
      }
      float iv = 1.f / (1.f + expf(-ys[0]));
      float fv = 1.f / (1.f + expf(-ys[1]));
      float gv = tanhf(ys[2]);
      float ov = 1.f / (1.f + expf(-ys[3]));
      c = fv * c + iv * gv;
      float hv = ov * tanhf(c);
      h_loc[tid] = hv;
      int tout = t;
      if (dir) { tout = l - 1 - t; if (tout < 0) tout += T_; }
      out[((size_t)(b * T_ + tout) << 10) + (dir << 9) + (part << 7) + tid] = hv;
    }
    __syncthreads();

    // h exchange + 4-WG barrier via relaxed L3 atomics (skip after last step)
    if (t < T_ - 1) {
      if (tid < 64) {
        unsigned int* hb_w = hbuf + (((size_t)((t + 1) & 1) << 6) + grp) * 256;
        __hip_atomic_store(&hb_w[(part << 6) + tid],
                           packh2(h_loc[2 * tid], h_loc[2 * tid + 1]),
                           __ATOMIC_RELAXED, __HIP_MEMORY_SCOPE_AGENT);
      }
      // ensure this wave's h stores are L3-visible before flag release
      asm volatile("s_waitcnt vmcnt(0)" ::: "memory");
      __syncthreads();
      if (tid == 0)
        __hip_atomic_store(myflag, t + 1, __ATOMIC_RELAXED,
                           __HIP_MEMORY_SCOPE_AGENT);
      if (tid < 4) {
        while (__hip_atomic_load(gflags + (tid << 5), __ATOMIC_RELAXED,
                                 __HIP_MEMORY_SCOPE_AGENT) < t + 1)
          __builtin_amdgcn_s_sleep(1);
      }
      __syncthreads();
    }
  }
}

extern "C" void kernel_launch(void* const* d_in, const int* in_sizes, int n_in,
                              void* d_out, int out_size, void* d_ws, size_t ws_size,
                              hipStream_t stream) {
  const float* x       = (const float*)d_in[0];
  const int*   lengths = (const int*)d_in[1];
  const float* Wi_f    = (const float*)d_in[2];
  const float* Wh_f    = (const float*)d_in[3];
  const float* b_f     = (const float*)d_in[4];
  const float* Wi_b    = (const float*)d_in[5];
  const float* Wh_b    = (const float*)d_in[6];
  const float* b_b     = (const float*)d_in[7];
  float* out = (float*)d_out;

  unsigned int* xs    = (unsigned int*)d_ws;            // 128 MiB (f16 pairs)
  unsigned int* wpack = xs + (size_t)2 * M_ * 1024;     // 4 MiB
  unsigned int* hbuf  = wpack + (size_t)2 * 4 * 256 * 512;  // 128 KiB
  int*          flags = (int*)(hbuf + 2 * 64 * 256);    // 32 KiB

  pack_wh<<<dim3(2048), 512, 0, stream>>>(Wh_f, Wh_b, wpack);
  zero_ws<<<dim3(80), 512, 0, stream>>>(hbuf);   // hbuf (32768) + flags (8192)

  dim3 g1(M_ / 64, G_ / 64, 2);
  xs_gemm<<<g1, 256, 0, stream>>>(x, lengths, Wi_f, b_f, Wi_b, b_b, xs);

  lstm_rec5<<<dim3(256), 512, 0, stream>>>(xs, wpack, hbuf, flags, lengths, out);
}

// Round 6
// 2886.563 us; speedup vs baseline: 12.6409x; 1.5265x over previous
//
#include <hip/hip_runtime.h>
#include <math.h>

#define B_ 32
#define T_ 512
#define D_ 512
#define H_ 512
#define G_ 2048        // 4*H
#define M_ (B_ * T_)   // 16384

typedef _Float16 half2v __attribute__((ext_vector_type(2)));
typedef _Float16 f16x8  __attribute__((ext_vector_type(8)));
typedef float    f32x4  __attribute__((ext_vector_type(4)));

static __device__ __forceinline__ unsigned short f2h(float f) {
  return __builtin_bit_cast(unsigned short, (_Float16)f);
}
static __device__ __forceinline__ float h2f(unsigned short u) {
  return (float)__builtin_bit_cast(_Float16, u);
}
static __device__ __forceinline__ unsigned int packh2(float a, float b) {
  return (unsigned int)f2h(a) | ((unsigned int)f2h(b) << 16);
}

// -----------------------------------------------------------------------------
// Pack Wh fp32 [512][2048] -> MFMA-B fragment-linear f16:
//   wfrag[dir][w(32)][n(4)][kb(16)][lane(64)][j(8)]
//   element = Wh[k = kb*32 + (lane>>4)*8 + j][col = n*512 + w*16 + (lane&15)]
// -----------------------------------------------------------------------------
__global__ __launch_bounds__(512) void pack_wfrag(
    const float* __restrict__ Wh_f, const float* __restrict__ Wh_b,
    uint4* __restrict__ wfrag)
{
  int gid = blockIdx.x * 512 + threadIdx.x;   // 0..262143
  int lane = gid & 63;
  int kb   = (gid >> 6) & 15;
  int n    = (gid >> 10) & 3;
  int w    = (gid >> 12) & 31;
  int dir  = gid >> 17;
  const float* Wh = dir ? Wh_b : Wh_f;
  int k0 = kb * 32 + (lane >> 4) * 8;
  int c  = n * 512 + w * 16 + (lane & 15);
  const float* p = Wh + (size_t)k0 * G_ + c;
  uint4 o;
  o.x = packh2(p[0],        p[(size_t)1 * G_]);
  o.y = packh2(p[(size_t)2 * G_], p[(size_t)3 * G_]);
  o.z = packh2(p[(size_t)4 * G_], p[(size_t)5 * G_]);
  o.w = packh2(p[(size_t)6 * G_], p[(size_t)7 * G_]);
  wfrag[gid] = o;
}

// zero hbuf (32768 uints) + flags (8192 ints) = 40960 words
__global__ __launch_bounds__(512) void zero_ws(unsigned int* p) {
  p[blockIdx.x * 512 + threadIdx.x] = 0u;
}

// -----------------------------------------------------------------------------
// GEMM: xs[dir][m][g] (f16 pairs, ORIGINAL col order) = A_dir @ Wi_dir + bias
// -----------------------------------------------------------------------------
__global__ __launch_bounds__(256) void xs_gemm(
    const float* __restrict__ x, const int* __restrict__ lengths,
    const float* __restrict__ Wi_f, const float* __restrict__ bf,
    const float* __restrict__ Wi_b, const float* __restrict__ bb,
    unsigned int* __restrict__ xs)   // f16 pairs, 1024 uints per row
{
  const int dir = blockIdx.z;
  const float* Wi   = dir ? Wi_b : Wi_f;
  const float* bias = dir ? bb : bf;
  unsigned int* outp = xs + (size_t)dir * ((size_t)M_ * 1024);
  const int m0 = blockIdx.x * 64;
  const int n0 = blockIdx.y * 64;

  __shared__ __attribute__((aligned(16))) float As[32][68];
  __shared__ __attribute__((aligned(16))) float Bs[32][68];

  const int tid = threadIdx.x;
  const int tx = tid & 15, ty = tid >> 4;
  const int arow = tid >> 3;
  const int acol = (tid & 7) << 2;
  const int brow = tid >> 4;
  const int bcol = (tid & 15) << 2;

  size_t abase[2];
#pragma unroll
  for (int r = 0; r < 2; ++r) {
    int m = m0 + arow + r * 32;
    int bidx = m >> 9, t = m & 511;
    int s = t;
    if (dir) { int l = lengths[bidx]; s = l - 1 - t; if (s < 0) s += T_; }
    abase[r] = ((size_t)bidx * T_ + s) * D_;
  }

  float acc[4][4] = {{0.f}};

  for (int k0 = 0; k0 < D_; k0 += 32) {
#pragma unroll
    for (int r = 0; r < 2; ++r) {
      float4 av = *(const float4*)(x + abase[r] + (k0 + acol));
      int row = arow + r * 32;
      As[acol + 0][row] = av.x;
      As[acol + 1][row] = av.y;
      As[acol + 2][row] = av.z;
      As[acol + 3][row] = av.w;
    }
#pragma unroll
    for (int r = 0; r < 2; ++r) {
      int kk = brow + r * 16;
      float4 bv = *(const float4*)(Wi + (size_t)(k0 + kk) * G_ + n0 + bcol);
      *(float4*)&Bs[kk][bcol] = bv;
    }
    __syncthreads();
#pragma unroll
    for (int kk = 0; kk < 32; ++kk) {
      float4 a4 = *(const float4*)&As[kk][ty << 2];
      float4 b4 = *(const float4*)&Bs[kk][tx << 2];
      float a_[4] = {a4.x, a4.y, a4.z, a4.w};
      float b_[4] = {b4.x, b4.y, b4.z, b4.w};
#pragma unroll
      for (int i = 0; i < 4; ++i)
#pragma unroll
        for (int j = 0; j < 4; ++j)
          acc[i][j] = fmaf(a_[i], b_[j], acc[i][j]);
    }
    __syncthreads();
  }

  float4 bias4 = *(const float4*)(bias + n0 + (tx << 2));
  float bb4[4] = {bias4.x, bias4.y, bias4.z, bias4.w};
#pragma unroll
  for (int i = 0; i < 4; ++i) {
    int m = m0 + (ty << 2) + i;
    uint2 o;
    o.x = packh2(acc[i][0] + bb4[0], acc[i][1] + bb4[1]);
    o.y = packh2(acc[i][2] + bb4[2], acc[i][3] + bb4[3]);
    *(uint2*)(outp + (size_t)m * 1024 + ((n0 + (tx << 2)) >> 1)) = o;
  }
}

// -----------------------------------------------------------------------------
// Recurrence v6: MFMA + register-resident weights.
// 256 WGs. xcd=bid&7 -> dir=xcd>>2, batch octet xslot=xcd&3; w=bid>>3 owns
// 16 hidden units (64 gate cols) for all 8 batches. Closed 32-WG sync group
// per XCD (relaxed-atomic flags, r5-proven). Weight slice (64 KB f16) loaded
// ONCE into VGPRs (8 uint4/lane). Per step: h stage (8 KB, relaxed L3 loads)
// -> 8x mfma_f32_16x16x32_f16 per wave (A=h from LDS, B=W from regs) ->
// gates -> f16 h exchange + 32-flag barrier.
// -----------------------------------------------------------------------------
__global__ __launch_bounds__(512) void lstm_rec6(
    const unsigned int* __restrict__ xs,      // f16 pairs, plain layout
    const uint4* __restrict__ wfrag,          // fragment-linear f16
    unsigned int* __restrict__ hbuf,          // [2][8grp][2048 uints]
    int* __restrict__ flags,                  // [8grp][32wg][32pad]
    const int* __restrict__ lengths,
    float* __restrict__ out)
{
  const int bid   = blockIdx.x;
  const int xcd   = bid & 7;
  const int w     = bid >> 3;           // unit-slice 0..31, U0 = 16w
  const int dir   = xcd >> 2;
  const int xslot = xcd & 3;            // batch octet: batches 8*xslot..+7
  const int grp   = xcd;
  const int U0    = w << 4;

  __shared__ uint4 h4[64 * 17];         // A-frags, padded (17 uint4 per kk)
  __shared__ float y_lds[2 * 4 * 8 * 16];
  __shared__ float h_loc[128];

  const int tid  = threadIdx.x;
  const int lane = tid & 63;
  const int wvid = tid >> 6;            // 0..7
  const int n    = wvid & 3;            // gate / ntile
  const int kh   = wvid >> 2;           // K half
  unsigned int* h4u = (unsigned int*)h4;

  // ---- one-time: weight slice into registers (64 KB / WG) ----
  const uint4* wbase = wfrag + ((size_t)(dir * 32 + w) << 12)
                             + ((n * 16 + kh * 8) << 6) + lane;
  uint4 wreg[8];
#pragma unroll
  for (int i = 0; i < 8; ++i) wreg[i] = wbase[i << 6];

  // zero A-frag LDS (incl. pad rows b=8..15, never written again)
  for (int i = tid; i < 64 * 68; i += 512) h4u[i] = 0u;

  // gate-phase constants
  const int gb = tid >> 4;              // batch 0..7 (tid<128)
  const int gu = tid & 15;              // unit 0..15
  const int b_glob = xslot * 8 + gb;
  const int l = lengths[(tid < 128) ? b_glob : 0];
  const unsigned short* xs16 = (const unsigned short*)xs;
  const size_t xs_base = ((size_t)dir * M_ + (size_t)b_glob * T_) * 2048 + U0 + gu;
  float c = 0.f;

  int* gflags = flags + (grp << 10);    // [32 wg][32 pad]
  __syncthreads();

  for (int t = 0; t < T_; ++t) {
    // 1. stage h: 2048 uints (8 batches x 512 units f16) -> LDS frag layout
    {
      const unsigned int* hb_r = hbuf + (((size_t)(t & 1) * 8 + grp) << 11);
#pragma unroll
      for (int s = 0; s < 4; ++s) {
        int i = tid + (s << 9);         // i<2048: kk=i>>5, r=i&31 (b*4+jp)
        unsigned int v = 0u;
        if (t != 0)
          v = __hip_atomic_load(&hb_r[i], __ATOMIC_RELAXED,
                                __HIP_MEMORY_SCOPE_AGENT);
        h4u[((i >> 5) * 68) + (i & 31)] = v;
      }
    }
    __syncthreads();

    // 2. MFMA: y[16][16] partial (this wave: ntile n, K half kh)
    f32x4 acc = {0.f, 0.f, 0.f, 0.f};
#pragma unroll
    for (int i = 0; i < 8; ++i) {
      int kb = kh * 8 + i;
      uint4 hv = h4[((kb << 2) + (lane >> 4)) * 17 + (lane & 15)];
      acc = __builtin_amdgcn_mfma_f32_16x16x32_f16(
          __builtin_bit_cast(f16x8, hv), __builtin_bit_cast(f16x8, wreg[i]),
          acc, 0, 0, 0);
    }
    // store rows<8 to y_lds[kh][n][row][col]
    {
      int rowg = lane >> 4;
      if (rowg < 2) {
        int col = lane & 15;
        float* yp = y_lds + ((kh << 2) + n) * 128 + (rowg << 6) + col;
#pragma unroll
        for (int r = 0; r < 4; ++r) yp[r << 4] = acc[r];
      }
    }
    __syncthreads();

    // 3. gates (tid<128): batch gb, unit gu
    if (tid < 128) {
      const unsigned short* xr = xs16 + xs_base + ((size_t)t << 11);
      int base = (gb << 4) + gu;
      float ys[4];
#pragma unroll
      for (int g = 0; g < 4; ++g)
        ys[g] = y_lds[(g << 7) + base] + y_lds[((4 + g) << 7) + base]
              + h2f(xr[g << 9]);
      float iv = 1.f / (1.f + expf(-ys[0]));
      float fv = 1.f / (1.f + expf(-ys[1]));
      float gv = tanhf(ys[2]);
      float ov = 1.f / (1.f + expf(-ys[3]));
      c = fv * c + iv * gv;
      float hv = ov * tanhf(c);
      h_loc[(gb << 4) + gu] = hv;
      int tout = t;
      if (dir) { tout = l - 1 - t; if (tout < 0) tout += T_; }
      out[(((size_t)b_glob * T_ + tout) << 10) + (dir << 9) + U0 + gu] = hv;
    }
    __syncthreads();

    // 4. h exchange (f16 pairs) + 32-WG relaxed-flag barrier
    if (t < T_ - 1) {
      if (tid < 64) {
        int pb = tid >> 3, up = tid & 7;          // batch, unit-pair
        int kk = 2 * w + (up >> 2);
        int idx = (kk << 5) + (pb << 2) + (up & 3);
        unsigned int* hb_w = hbuf + (((size_t)((t + 1) & 1) * 8 + grp) << 11);
        __hip_atomic_store(&hb_w[idx],
                           packh2(h_loc[(pb << 4) + 2 * up],
                                  h_loc[(pb << 4) + 2 * up + 1]),
                           __ATOMIC_RELAXED, __HIP_MEMORY_SCOPE_AGENT);
      }
      asm volatile("s_waitcnt vmcnt(0)" ::: "memory");
      __syncthreads();
      if (tid == 0)
        __hip_atomic_store(gflags + (w << 5), t + 1, __ATOMIC_RELAXED,
                           __HIP_MEMORY_SCOPE_AGENT);
      if (tid < 32) {
        while (__hip_atomic_load(gflags + (tid << 5), __ATOMIC_RELAXED,
                                 __HIP_MEMORY_SCOPE_AGENT) < t + 1)
          __builtin_amdgcn_s_sleep(1);
      }
      __syncthreads();
    }
  }
}

extern "C" void kernel_launch(void* const* d_in, const int* in_sizes, int n_in,
                              void* d_out, int out_size, void* d_ws, size_t ws_size,
                              hipStream_t stream) {
  const float* x       = (const float*)d_in[0];
  const int*   lengths = (const int*)d_in[1];
  const float* Wi_f    = (const float*)d_in[2];
  const float* Wh_f    = (const float*)d_in[3];
  const float* b_f     = (const float*)d_in[4];
  const float* Wi_b    = (const float*)d_in[5];
  const float* Wh_b    = (const float*)d_in[6];
  const float* b_b     = (const float*)d_in[7];
  float* out = (float*)d_out;

  unsigned int* xs    = (unsigned int*)d_ws;          // 128 MiB (f16 pairs)
  uint4*        wfrag = (uint4*)(xs + (size_t)2 * M_ * 1024);   // 4 MiB
  unsigned int* hbuf  = (unsigned int*)(wfrag + 262144);        // 128 KiB
  int*          flags = (int*)(hbuf + 2 * 8 * 2048);            // 32 KiB

  pack_wfrag<<<dim3(512), 512, 0, stream>>>(Wh_f, Wh_b, wfrag);
  zero_ws<<<dim3(80), 512, 0, stream>>>(hbuf);   // hbuf(32768) + flags(8192)

  dim3 g1(M_ / 64, G_ / 64, 2);
  xs_gemm<<<g1, 256, 0, stream>>>(x, lengths, Wi_f, b_f, Wi_b, b_b, xs);

  lstm_rec6<<<dim3(256), 512, 0, stream>>>(xs, wfrag, hbuf, flags, lengths, out);
}

// Round 7
// 1846.169 us; speedup vs baseline: 19.7646x; 1.5635x over previous
//
#include <hip/hip_runtime.h>
#include <math.h>

#define B_ 32
#define T_ 512
#define D_ 512
#define H_ 512
#define G_ 2048        // 4*H
#define M_ (B_ * T_)   // 16384

typedef _Float16 f16x8  __attribute__((ext_vector_type(8)));
typedef float    f32x4  __attribute__((ext_vector_type(4)));

static __device__ __forceinline__ unsigned short f2h(float f) {
  return __builtin_bit_cast(unsigned short, (_Float16)f);
}
static __device__ __forceinline__ unsigned int packh2(float a, float b) {
  return (unsigned int)f2h(a) | ((unsigned int)f2h(b) << 16);
}

// -----------------------------------------------------------------------------
// Pack x fp32 [32][512][512] -> f16 pairs, same layout. uint gid = (b*T+t)*256+u
// -----------------------------------------------------------------------------
__global__ __launch_bounds__(512) void pack_xh(
    const float* __restrict__ x, unsigned int* __restrict__ xh)
{
  size_t gid = (size_t)blockIdx.x * 512 + threadIdx.x;   // 0..4194303
  float2 v = *(const float2*)(x + gid * 2);
  xh[gid] = packh2(v.x, v.y);
}

// -----------------------------------------------------------------------------
// Pack Wh AND Wi fp32 [512][2048] -> MFMA-B fragment-linear f16:
//   wfrag[which][dir][w(32)][n(4)][kb(16)][lane(64)]  (uint4 each, j=8 f16)
//   element = W[k = kb*32 + (lane>>4)*8 + j][col = n*512 + w*16 + (lane&15)]
// -----------------------------------------------------------------------------
__global__ __launch_bounds__(512) void pack_wfrag(
    const float* __restrict__ Wh_f, const float* __restrict__ Wh_b,
    const float* __restrict__ Wi_f, const float* __restrict__ Wi_b,
    uint4* __restrict__ wfrag)
{
  int gid = blockIdx.x * 512 + threadIdx.x;   // 0..524287
  int lane  = gid & 63;
  int kb    = (gid >> 6) & 15;
  int n     = (gid >> 10) & 3;
  int w     = (gid >> 12) & 31;
  int dir   = (gid >> 17) & 1;
  int which = gid >> 18;                       // 0 = Wh, 1 = Wi
  const float* W = which ? (dir ? Wi_b : Wi_f) : (dir ? Wh_b : Wh_f);
  int k0 = kb * 32 + (lane >> 4) * 8;
  int c  = n * 512 + w * 16 + (lane & 15);
  const float* p = W + (size_t)k0 * G_ + c;
  uint4 o;
  o.x = packh2(p[0],              p[(size_t)1 * G_]);
  o.y = packh2(p[(size_t)2 * G_], p[(size_t)3 * G_]);
  o.z = packh2(p[(size_t)4 * G_], p[(size_t)5 * G_]);
  o.w = packh2(p[(size_t)6 * G_], p[(size_t)7 * G_]);
  wfrag[gid] = o;
}

// zero the flag area (8192 ints)
__global__ __launch_bounds__(512) void zero_flags(int* p) {
  p[blockIdx.x * 512 + threadIdx.x] = 0;
}

// -----------------------------------------------------------------------------
// Recurrence v7: fully fused (input projection + recurrence), MFMA,
// register-resident Wi AND Wh (16 uint4/lane). 256 WGs; xcd=bid&7 ->
// (dir, batch octet); w=bid>>3 -> 16-unit slice. Per step:
//   x-stage (8KB, L2-shared) -> 8 x-MFMAs  [independent of h -> hides latency]
//   poll h flags -> h-stage -> 8 h-MFMAs -> y reduce -> gates (+bias)
//   h publish (relaxed L3) -> vmcnt(0) -> flag release -> out store (deferred,
//   off critical path; its ack absorbed by NEXT step's vmcnt).
// -----------------------------------------------------------------------------
__global__ __launch_bounds__(512) void lstm_rec7(
    const unsigned int* __restrict__ xh,      // f16 pairs [b][t][256]
    const uint4* __restrict__ wfrag,          // [which][dir][w][n][kb][lane]
    unsigned int* __restrict__ hbuf,          // [2][8grp][2048 uints]
    int* __restrict__ flags,                  // [8grp][32wg][32pad]
    const int* __restrict__ lengths,
    const float* __restrict__ bf, const float* __restrict__ bb,
    float* __restrict__ out)
{
  const int bid   = blockIdx.x;
  const int xcd   = bid & 7;
  const int w     = bid >> 3;           // unit-slice 0..31, U0 = 16w
  const int dir   = xcd >> 2;
  const int xslot = xcd & 3;            // batch octet: batches 8*xslot..+7
  const int grp   = xcd;
  const int U0    = w << 4;

  __shared__ uint4 h4[64 * 17];         // h A-frags, padded rows (17 uint4)
  __shared__ uint4 x4[64 * 17];         // x A-frags, same layout
  __shared__ float y_lds[2 * 4 * 8 * 16];
  __shared__ float h_loc[128];
  __shared__ int   l_sh[8];

  const int tid  = threadIdx.x;
  const int lane = tid & 63;
  const int wvid = tid >> 6;            // 0..7
  const int n    = wvid & 3;            // gate / ntile
  const int kh   = wvid >> 2;           // K half
  unsigned int* h4u = (unsigned int*)h4;
  unsigned int* x4u = (unsigned int*)x4;

  // ---- one-time: weight slices into registers (2 x 64 KB / WG) ----
  const uint4* whb = wfrag + ((size_t)(dir * 32 + w) << 12)
                           + ((n * 16 + kh * 8) << 6) + lane;
  const uint4* wib = whb + (1 << 18);   // Wi frags
  uint4 wregh[8], wregi[8];
#pragma unroll
  for (int i = 0; i < 8; ++i) { wregh[i] = whb[i << 6]; wregi[i] = wib[i << 6]; }

  // zero frag LDS (pad rows r=8..15 + tail never written again)
  for (int i = tid; i < 64 * 68; i += 512) { h4u[i] = 0u; x4u[i] = 0u; }
  if (tid < 8) l_sh[tid] = lengths[xslot * 8 + tid];

  // gate-phase constants
  const int gb = tid >> 4;              // batch 0..7 (tid<128)
  const int gu = tid & 15;              // unit 0..15
  const int b_glob = xslot * 8 + gb;
  const float* bdir = dir ? bb : bf;
  float bias_r[4] = {0.f, 0.f, 0.f, 0.f};
  if (tid < 128) {
#pragma unroll
    for (int g = 0; g < 4; ++g) bias_r[g] = bdir[(g << 9) + U0 + gu];
  }
  float c = 0.f;
  float hv_keep = 0.f;
  int   tout_keep = 0;

  // x-stage per-thread constants: r fixed per thread
  const int xr   = (tid >> 2) & 7;      // batch within octet
  const int xw_  = tid & 3;             // word
  const int xkk0 = tid >> 5;            // kk base (s adds 16)
  const size_t xrowstride = 256;
  const size_t xbbase = ((size_t)(xslot * 8 + xr)) * T_;

  int* gflags = flags + (grp << 10);    // [32 wg][32 pad]
  __syncthreads();
  const int l_x = l_sh[xr];

  for (int t = 0; t < T_; ++t) {
    // 1. x-stage: 4 uints/thread into x4 (conflict-free b32 pattern)
    {
      int srow = t;
      if (dir) { srow = l_x - 1 - t; if (srow < 0) srow += T_; }
      const unsigned int* xsrc = xh + (xbbase + srow) * xrowstride;
#pragma unroll
      for (int s = 0; s < 4; ++s) {
        int kk = xkk0 + (s << 4);
        x4u[kk * 68 + (xr << 2) + xw_] = xsrc[(kk << 2) + xw_];
      }
    }
    __syncthreads();

    // 2. x-MFMAs (independent of h(t))
    f32x4 acc = {0.f, 0.f, 0.f, 0.f};
#pragma unroll
    for (int i = 0; i < 8; ++i) {
      int kb = kh * 8 + i;
      uint4 av = x4[((kb << 2) + (lane >> 4)) * 17 + (lane & 15)];
      acc = __builtin_amdgcn_mfma_f32_16x16x32_f16(
          __builtin_bit_cast(f16x8, av), __builtin_bit_cast(f16x8, wregi[i]),
          acc, 0, 0, 0);
    }

    // 3. wait for h(t) (wave 0 polls), then stage h + h-MFMAs
    if (t > 0) {
      if (tid < 32) {
        while (__hip_atomic_load(gflags + (tid << 5), __ATOMIC_RELAXED,
                                 __HIP_MEMORY_SCOPE_AGENT) < t)
          __builtin_amdgcn_s_sleep(1);
      }
      __syncthreads();
      {
        const unsigned int* hb_r = hbuf + (((size_t)(t & 1) * 8 + grp) << 11);
#pragma unroll
        for (int s = 0; s < 4; ++s) {
          int i = tid + (s << 9);
          h4u[((i >> 5) * 68) + (i & 31)] =
              __hip_atomic_load(&hb_r[i], __ATOMIC_RELAXED,
                                __HIP_MEMORY_SCOPE_AGENT);
        }
      }
      __syncthreads();
#pragma unroll
      for (int i = 0; i < 8; ++i) {
        int kb = kh * 8 + i;
        uint4 hv = h4[((kb << 2) + (lane >> 4)) * 17 + (lane & 15)];
        acc = __builtin_amdgcn_mfma_f32_16x16x32_f16(
            __builtin_bit_cast(f16x8, hv), __builtin_bit_cast(f16x8, wregh[i]),
            acc, 0, 0, 0);
      }
    } else {
      __syncthreads();   // keep barrier count uniform-ish (poll skipped at t=0)
    }

    // 4. y partials -> LDS (rows < 8 = real batches)
    {
      int rowg = lane >> 4;
      if (rowg < 2) {
        int col = lane & 15;
        float* yp = y_lds + ((kh << 2) + n) * 128 + (rowg << 6) + col;
#pragma unroll
        for (int r = 0; r < 4; ++r) yp[r << 4] = acc[r];
      }
    }
    __syncthreads();

    // 5. gates (tid<128): batch gb, unit gu
    if (tid < 128) {
      int base = (gb << 4) + gu;
      float ys[4];
#pragma unroll
      for (int g = 0; g < 4; ++g)
        ys[g] = y_lds[(g << 7) + base] + y_lds[((4 + g) << 7) + base] + bias_r[g];
      float iv = 1.f / (1.f + expf(-ys[0]));
      float fv = 1.f / (1.f + expf(-ys[1]));
      float gv = tanhf(ys[2]);
      float ov = 1.f / (1.f + expf(-ys[3]));
      c = fv * c + iv * gv;
      float hv = ov * tanhf(c);
      h_loc[base] = hv;
      int tout = t;
      if (dir) { tout = l_sh[gb] - 1 - t; if (tout < 0) tout += T_; }
      hv_keep = hv; tout_keep = tout;
    }
    __syncthreads();

    // 6. h publish + flag release (out store deferred below)
    if (t < T_ - 1) {
      if (tid < 64) {
        int pb = tid >> 3, up = tid & 7;          // batch, unit-pair
        int kk = 2 * w + (up >> 2);
        int idx = (kk << 5) + (pb << 2) + (up & 3);
        unsigned int* hb_w = hbuf + (((size_t)((t + 1) & 1) * 8 + grp) << 11);
        __hip_atomic_store(&hb_w[idx],
                           packh2(h_loc[(pb << 4) + 2 * up],
                                  h_loc[(pb << 4) + 2 * up + 1]),
                           __ATOMIC_RELAXED, __HIP_MEMORY_SCOPE_AGENT);
      }
      asm volatile("s_waitcnt vmcnt(0)" ::: "memory");
      __syncthreads();
      if (tid == 0)
        __hip_atomic_store(gflags + (w << 5), t + 1, __ATOMIC_RELAXED,
                           __HIP_MEMORY_SCOPE_AGENT);
    }

    // 7. out store — fire-and-forget, off the flag critical path
    if (tid < 128)
      out[(((size_t)b_glob * T_ + tout_keep) << 10) + (dir << 9) + U0 + gu] =
          hv_keep;
  }
}

extern "C" void kernel_launch(void* const* d_in, const int* in_sizes, int n_in,
                              void* d_out, int out_size, void* d_ws, size_t ws_size,
                              hipStream_t stream) {
  const float* x       = (const float*)d_in[0];
  const int*   lengths = (const int*)d_in[1];
  const float* Wi_f    = (const float*)d_in[2];
  const float* Wh_f    = (const float*)d_in[3];
  const float* b_f     = (const float*)d_in[4];
  const float* Wi_b    = (const float*)d_in[5];
  const float* Wh_b    = (const float*)d_in[6];
  const float* b_b     = (const float*)d_in[7];
  float* out = (float*)d_out;

  unsigned int* xh    = (unsigned int*)d_ws;                    // 16 MiB
  uint4*        wfrag = (uint4*)(xh + (size_t)4194304);         // 8 MiB (Wh+Wi)
  unsigned int* hbuf  = (unsigned int*)(wfrag + 524288);        // 128 KiB
  int*          flags = (int*)(hbuf + 2 * 8 * 2048);            // 32 KiB

  pack_xh<<<dim3(8192), 512, 0, stream>>>(x, xh);
  pack_wfrag<<<dim3(1024), 512, 0, stream>>>(Wh_f, Wh_b, Wi_f, Wi_b, wfrag);
  zero_flags<<<dim3(16), 512, 0, stream>>>(flags);

  lstm_rec7<<<dim3(256), 512, 0, stream>>>(xh, wfrag, hbuf, flags, lengths,
                                           b_f, b_b, out);
}